// Round 2
// baseline (554.276 us; speedup 1.0000x reference)
//
#include <hip/hip_runtime.h>
#include <stdint.h>

// Problem constants
#define NODES 4096
#define EDGES 16384
#define CSTR  288   // padded GEMM column count: 4 heads * 72 (64 P + qhi + qlo + 6 zero)

typedef __attribute__((ext_vector_type(4))) float    f32x4;
typedef __attribute__((ext_vector_type(8))) short    short8;
typedef __attribute__((ext_vector_type(4))) uint32_t u32x4;
typedef __attribute__((ext_vector_type(4))) unsigned short u16x4;

__device__ __forceinline__ unsigned short f2bf(float f) {
  union { float f; uint32_t u; } v; v.f = f;
  uint32_t u = v.u;
  return (unsigned short)((u + 0x7fffu + ((u >> 16) & 1u)) >> 16);  // RTNE
}
__device__ __forceinline__ float bf2f(unsigned short s) {
  union { uint32_t u; float f; } v; v.u = ((uint32_t)s) << 16;
  return v.f;
}

// ---------------------------------------------------------------------------
// K1: per 8 nodes: t = nf@W1[h]+b1  ->  P = t@W2[h], q = t.Wa[h]
// Output PqT bf16 [288][4096]: row h*72+o (o<64)=P, +64=q_hi, +65=q_lo, rest 0
// ---------------------------------------------------------------------------
__global__ __launch_bounds__(256) void k1_prep(
    const float* __restrict__ nf, const float* __restrict__ W1,
    const float* __restrict__ b1, const float* __restrict__ Wa,
    const float* __restrict__ W2, unsigned short* __restrict__ PqT)
{
  __shared__ float nf_s[8][128];
  __shared__ float t_s[8][132];
  __shared__ float p_s[65][8];
  const int n0 = blockIdx.x * 8;
  const int t = threadIdx.x;
  for (int i = 0; i < 4; i++) {
    int idx = t + 256 * i;
    nf_s[idx >> 7][idx & 127] = nf[(size_t)(n0 + (idx >> 7)) * 128 + (idx & 127)];
  }
  for (int h = 0; h < 4; h++) {
    __syncthreads();
    {
      const int k = t & 127, ng = t >> 7;
      float a0 = b1[h * 128 + k], a1 = a0, a2 = a0, a3 = a0;
      const float* w1p = W1 + (size_t)h * 128 * 128 + k;
      for (int d = 0; d < 128; d++) {
        float wv = w1p[(size_t)d * 128];
        a0 += nf_s[ng * 4 + 0][d] * wv;
        a1 += nf_s[ng * 4 + 1][d] * wv;
        a2 += nf_s[ng * 4 + 2][d] * wv;
        a3 += nf_s[ng * 4 + 3][d] * wv;
      }
      t_s[ng * 4 + 0][k] = a0; t_s[ng * 4 + 1][k] = a1;
      t_s[ng * 4 + 2][k] = a2; t_s[ng * 4 + 3][k] = a3;
    }
    __syncthreads();
    {
      const int o = t & 63, ng = t >> 6;
      float a0 = 0.f, a1 = 0.f;
      const float* w2p = W2 + (size_t)h * 128 * 64 + o;
      for (int k = 0; k < 128; k++) {
        float wv = w2p[(size_t)k * 64];
        a0 += t_s[ng * 2 + 0][k] * wv;
        a1 += t_s[ng * 2 + 1][k] * wv;
      }
      p_s[o][ng * 2 + 0] = a0; p_s[o][ng * 2 + 1] = a1;
    }
    if (t < 8) {
      float a = 0.f;
      for (int k = 0; k < 128; k++) a += t_s[t][k] * Wa[h * 128 + k];
      p_s[64][t] = a;
    }
    __syncthreads();
    if (t < 72) {
      unsigned short tmp[8];
      if (t < 64) {
        for (int j = 0; j < 8; j++) tmp[j] = f2bf(p_s[t][j]);
      } else if (t == 64) {
        for (int j = 0; j < 8; j++) tmp[j] = f2bf(p_s[64][j]);
      } else if (t == 65) {
        for (int j = 0; j < 8; j++) {
          unsigned short hi = f2bf(p_s[64][j]);
          tmp[j] = f2bf(p_s[64][j] - bf2f(hi));
        }
      } else {
        for (int j = 0; j < 8; j++) tmp[j] = 0;
      }
      u32x4 pk;
      pk[0] = (uint32_t)tmp[0] | ((uint32_t)tmp[1] << 16);
      pk[1] = (uint32_t)tmp[2] | ((uint32_t)tmp[3] << 16);
      pk[2] = (uint32_t)tmp[4] | ((uint32_t)tmp[5] << 16);
      pk[3] = (uint32_t)tmp[6] | ((uint32_t)tmp[7] << 16);
      *(u32x4*)(&PqT[(size_t)(h * 72 + t) * 4096 + n0]) = pk;
    }
  }
}

// ---------------------------------------------------------------------------
// K2: C[16384][288] = inc^T (f32->bf16 hi+lo on the fly) @ PqT^T
// MFMA 16x16x32 bf16. BM=64 (edges), BK=64 (nodes), full N=288 per block;
// 256 threads = 4 waves (2x2), each wave computes 32e x 144c = 2x9 fragments.
// The inc_lo correction MFMA is applied ONLY to the ni=4 and ni=8 fragments
// (the ones containing the q score columns of all 4 heads) so scores get
// full-fp32-inc precision; P columns keep plain bf16 inc (error ~1e-3 at out).
// LDS: A-tile hi + A-tile lo bf16 [64e][64k] (XOR/rotation chunk swizzle);
//      B-tile bf16 [288c][64k] stride 72 (pad) -> all accesses <=2-way.
// ---------------------------------------------------------------------------
__global__ __launch_bounds__(256) void k2_gemm(
    const float* __restrict__ inc, const unsigned short* __restrict__ PqT,
    float* __restrict__ C)
{
  __shared__ unsigned short As[64 * 64];    // 8 KB (inc hi)
  __shared__ unsigned short AsLo[64 * 64];  // 8 KB (inc lo residual)
  __shared__ unsigned short Bs[288 * 72];   // 41472 B
  const int t = threadIdx.x;
  const int lane = t & 63, w = t >> 6;
  const int wr = w & 1, wc = w >> 1;
  const int e0 = blockIdx.x * 64;
  const int eq = t & 15, kq = t >> 4;

  f32x4 acc[2][9];
  for (int mi = 0; mi < 2; mi++)
    for (int ni = 0; ni < 9; ni++)
      acc[mi][ni] = (f32x4){0.f, 0.f, 0.f, 0.f};

  f32x4 av[4];
  u32x4 bv[9];

  auto load_tiles = [&](int ks) {
    const float* ap = inc + (size_t)(ks * 64 + kq * 4) * 16384 + e0 + eq * 4;
#pragma unroll
    for (int r = 0; r < 4; r++)
      av[r] = *(const f32x4*)(ap + (size_t)r * 16384);
#pragma unroll
    for (int j = 0; j < 9; j++) {
      int f = t + 256 * j; int c = f >> 3, q8 = f & 7;
      bv[j] = *(const u32x4*)(PqT + (size_t)c * 4096 + ks * 64 + q8 * 8);
    }
  };
  auto store_tiles = [&]() {
#pragma unroll
    for (int i = 0; i < 4; i++) {
      int e = 4 * eq + i;
      int p = ((kq >> 1) + eq + 4 * i) & 7;  // chunk rotation: p = kc + perm(e)
      u16x4 wv, wl;
      wv[0] = f2bf(av[0][i]); wv[1] = f2bf(av[1][i]);
      wv[2] = f2bf(av[2][i]); wv[3] = f2bf(av[3][i]);
      wl[0] = f2bf(av[0][i] - bf2f(wv[0]));
      wl[1] = f2bf(av[1][i] - bf2f(wv[1]));
      wl[2] = f2bf(av[2][i] - bf2f(wv[2]));
      wl[3] = f2bf(av[3][i] - bf2f(wv[3]));
      *(u16x4*)(&As[e * 64 + p * 8 + (kq & 1) * 4]) = wv;
      *(u16x4*)(&AsLo[e * 64 + p * 8 + (kq & 1) * 4]) = wl;
    }
#pragma unroll
    for (int j = 0; j < 9; j++) {
      int f = t + 256 * j; int c = f >> 3, q8 = f & 7;
      *(u32x4*)(&Bs[c * 72 + q8 * 8]) = bv[j];
    }
  };
  auto compute = [&]() {
#pragma unroll
    for (int ksub = 0; ksub < 2; ksub++) {
      short8 afr[2], aflo[2];
      const int q = lane >> 4;
#pragma unroll
      for (int mi = 0; mi < 2; mi++) {
        int e = wr * 32 + mi * 16 + (lane & 15);
        int p = ((4 * ksub + q) + (e >> 2) + 4 * (e & 3)) & 7;
        afr[mi]  = *(const short8*)(&As[e * 64 + p * 8]);
        aflo[mi] = *(const short8*)(&AsLo[e * 64 + p * 8]);
      }
#pragma unroll
      for (int ni = 0; ni < 9; ni++) {
        int c = wc * 144 + ni * 16 + (lane & 15);
        const short8 bfr = *(const short8*)(&Bs[c * 72 + 32 * ksub + 8 * q]);
        acc[0][ni] = __builtin_amdgcn_mfma_f32_16x16x32_bf16(afr[0], bfr, acc[0][ni], 0, 0, 0);
        acc[1][ni] = __builtin_amdgcn_mfma_f32_16x16x32_bf16(afr[1], bfr, acc[1][ni], 0, 0, 0);
        if (ni == 4 || ni == 8) {  // fragments holding the q score columns
          acc[0][ni] = __builtin_amdgcn_mfma_f32_16x16x32_bf16(aflo[0], bfr, acc[0][ni], 0, 0, 0);
          acc[1][ni] = __builtin_amdgcn_mfma_f32_16x16x32_bf16(aflo[1], bfr, acc[1][ni], 0, 0, 0);
        }
      }
    }
  };

  load_tiles(0);
  for (int ks = 0; ks < 64; ks++) {
    __syncthreads();
    store_tiles();
    __syncthreads();
    if (ks < 63) load_tiles(ks + 1);
    compute();
  }

#pragma unroll
  for (int mi = 0; mi < 2; mi++)
#pragma unroll
    for (int ni = 0; ni < 9; ni++)
#pragma unroll
      for (int r = 0; r < 4; r++) {
        int e = e0 + wr * 32 + mi * 16 + (lane >> 4) * 4 + r;
        int c = wc * 144 + ni * 16 + (lane & 15);
        C[(size_t)e * CSTR + c] = acc[mi][ni][r];
      }
}

// ---------------------------------------------------------------------------
// K3: per head: scores = leaky_relu(C[:,h*72+64]+C[:,h*72+65]+ba), softmax
// ---------------------------------------------------------------------------
__global__ __launch_bounds__(1024) void k3_softmax(
    const float* __restrict__ C, const float* __restrict__ ba,
    float* __restrict__ coeff)
{
  const int h = blockIdx.x, t = threadIdx.x;
  __shared__ float red[16];
  float vals[16];
  float mx = -1e30f;
  const int cb = h * 72 + 64;
#pragma unroll
  for (int i = 0; i < 16; i++) {
    int e = t + 1024 * i;
    float s = C[(size_t)e * CSTR + cb] + C[(size_t)e * CSTR + cb + 1] + ba[h];
    s = (s > 0.f) ? s : 0.2f * s;
    vals[i] = s;
    mx = fmaxf(mx, s);
  }
  for (int off = 32; off > 0; off >>= 1) mx = fmaxf(mx, __shfl_xor(mx, off, 64));
  if ((t & 63) == 0) red[t >> 6] = mx;
  __syncthreads();
  float gmx = red[0];
  for (int i = 1; i < 16; i++) gmx = fmaxf(gmx, red[i]);
  float total = 0.f;
#pragma unroll
  for (int i = 0; i < 16; i++) { vals[i] = expf(vals[i] - gmx); total += vals[i]; }
  __syncthreads();
  for (int off = 32; off > 0; off >>= 1) total += __shfl_xor(total, off, 64);
  if ((t & 63) == 0) red[t >> 6] = total;
  __syncthreads();
  float gs = 0.f;
  for (int i = 0; i < 16; i++) gs += red[i];
  float inv = 1.f / gs;
#pragma unroll
  for (int i = 0; i < 16; i++) coeff[h * 16384 + t + 1024 * i] = vals[i] * inv;
}

// ---------------------------------------------------------------------------
// K4a/K4b: per-column (h,o) min/max over all edges of u = coeff*C  (b2 cancels)
// ---------------------------------------------------------------------------
__global__ __launch_bounds__(256) void k4_minmax(
    const float* __restrict__ C, const float* __restrict__ coeff,
    float* __restrict__ pmn, float* __restrict__ pmx)
{
  const int t = threadIdx.x, blk = blockIdx.x;
  const int h = t >> 6, o = t & 63, c = h * 72 + o;
  const int e0 = blk * 64;
  float mn = 1e30f, mx = -1e30f;
  for (int e = 0; e < 64; e++) {
    float u = coeff[h * 16384 + e0 + e] * C[(size_t)(e0 + e) * CSTR + c];
    mn = fminf(mn, u); mx = fmaxf(mx, u);
  }
  pmn[blk * 256 + t] = mn; pmx[blk * 256 + t] = mx;
}

__global__ __launch_bounds__(256) void k4_reduce(
    const float* __restrict__ pmn, const float* __restrict__ pmx,
    float* __restrict__ mnv, float* __restrict__ invv)
{
  const int t = threadIdx.x;
  float mn = 1e30f, mx = -1e30f;
  for (int b = 0; b < 256; b++) {
    mn = fminf(mn, pmn[b * 256 + t]);
    mx = fmaxf(mx, pmx[b * 256 + t]);
  }
  mnv[t] = mn;
  invv[t] = 1.f / (mx - mn + 1e-8f);
}

// ---------------------------------------------------------------------------
// K5: 16 edges/block: cat = relu((coeff*C - mn)*inv); out = cat@Wout + bout
// ---------------------------------------------------------------------------
__global__ __launch_bounds__(256) void k5_out(
    const float* __restrict__ C, const float* __restrict__ coeff,
    const float* __restrict__ mnv, const float* __restrict__ invv,
    const float* __restrict__ Wout, const float* __restrict__ bout,
    float* __restrict__ out)
{
  __shared__ float cat[16][256];
  const int t = threadIdx.x;
  const int e0 = blockIdx.x * 16;
  {
    const int h = t >> 6, o = t & 63, c = h * 72 + o;
    const float mn = mnv[t], inv = invv[t];
#pragma unroll
    for (int el = 0; el < 16; el++) {
      float u = coeff[h * 16384 + e0 + el] * C[(size_t)(e0 + el) * CSTR + c];
      float vn = (u - mn) * inv;
      cat[el][t] = vn > 0.f ? vn : 0.f;
    }
  }
  __syncthreads();
  {
    const int od = t & 63, eg = t >> 6;
    float b = bout[od];
    float a0 = b, a1 = b, a2 = b, a3 = b;
    for (int hc = 0; hc < 256; hc++) {
      float wv = Wout[(size_t)hc * 64 + od];
      a0 += cat[eg * 4 + 0][hc] * wv;
      a1 += cat[eg * 4 + 1][hc] * wv;
      a2 += cat[eg * 4 + 2][hc] * wv;
      a3 += cat[eg * 4 + 3][hc] * wv;
    }
    out[(size_t)(e0 + eg * 4 + 0) * 64 + od] = a0;
    out[(size_t)(e0 + eg * 4 + 1) * 64 + od] = a1;
    out[(size_t)(e0 + eg * 4 + 2) * 64 + od] = a2;
    out[(size_t)(e0 + eg * 4 + 3) * 64 + od] = a3;
  }
}

// ---------------------------------------------------------------------------
extern "C" void kernel_launch(void* const* d_in, const int* in_sizes, int n_in,
                              void* d_out, int out_size, void* d_ws, size_t ws_size,
                              hipStream_t stream) {
  const float* nf   = (const float*)d_in[0];
  const float* inc  = (const float*)d_in[1];
  const float* W1   = (const float*)d_in[2];
  const float* b1   = (const float*)d_in[3];
  const float* Wa   = (const float*)d_in[4];
  const float* ba   = (const float*)d_in[5];
  const float* W2   = (const float*)d_in[6];
  // d_in[7] = b2: cancels exactly in min-max normalization -> unused
  const float* Wout = (const float*)d_in[8];
  const float* bout = (const float*)d_in[9];
  float* out = (float*)d_out;

  char* ws = (char*)d_ws;
  unsigned short* PqT = (unsigned short*)(ws);            // 288*4096*2   = 2359296
  float* C     = (float*)(ws + 2359296);                  // 16384*288*4  = 18874368
  float* coeff = (float*)(ws + 21233664);                 // 4*16384*4    = 262144
  float* pmn   = (float*)(ws + 21495808);                 // 256*256*4    = 262144
  float* pmx   = (float*)(ws + 21757952);                 // 256*256*4    = 262144
  float* mnv   = (float*)(ws + 22020096);                 // 256*4
  float* invv  = (float*)(ws + 22021120);                 // 256*4

  k1_prep<<<512, 256, 0, stream>>>(nf, W1, b1, Wa, W2, PqT);
  k2_gemm<<<256, 256, 0, stream>>>(inc, PqT, C);
  k3_softmax<<<4, 1024, 0, stream>>>(C, ba, coeff);
  k4_minmax<<<256, 256, 0, stream>>>(C, coeff, pmn, pmx);
  k4_reduce<<<1, 256, 0, stream>>>(pmn, pmx, mnv, invv);
  k5_out<<<1024, 256, 0, stream>>>(C, coeff, mnv, invv, Wout, bout, out);
}

// Round 3
// 464.414 us; speedup vs baseline: 1.1935x; 1.1935x over previous
//
#include <hip/hip_runtime.h>
#include <stdint.h>

// Problem constants
#define NODES 4096
#define EDGES 16384
#define CSTR  288   // padded GEMM column count: 4 heads * 72 (64 P + qhi + qlo + 6 pad)

typedef __attribute__((ext_vector_type(4))) float    f32x4;
typedef __attribute__((ext_vector_type(8))) short    short8;
typedef __attribute__((ext_vector_type(4))) uint32_t u32x4;
typedef __attribute__((ext_vector_type(4))) unsigned short u16x4;

__device__ __forceinline__ unsigned short f2bf(float f) {
  union { float f; uint32_t u; } v; v.f = f;
  uint32_t u = v.u;
  return (unsigned short)((u + 0x7fffu + ((u >> 16) & 1u)) >> 16);  // RTNE
}
__device__ __forceinline__ float bf2f(unsigned short s) {
  union { uint32_t u; float f; } v; v.u = ((uint32_t)s) << 16;
  return v.f;
}
// order-preserving float <-> uint mapping for atomic min/max
__device__ __forceinline__ uint32_t fenc(float f) {
  uint32_t u = __float_as_uint(f);
  return (u >> 31) ? ~u : (u | 0x80000000u);
}
__device__ __forceinline__ float fdec(uint32_t k) {
  return (k & 0x80000000u) ? __uint_as_float(k ^ 0x80000000u) : __uint_as_float(~k);
}

// ---------------------------------------------------------------------------
// K0: fold weights through the linear chain.
// WeT[h][d][72]: o<64 -> (W1[h]@W2[h])[d][o];  o==64 -> (W1[h]@Wa[h])[d]
// beff[h][72]:   o<64 -> (b1[h]@W2[h])[o];     o==64 -> b1[h].Wa[h]
// grid 4*65 blocks x 128 threads (d = tid)
// ---------------------------------------------------------------------------
__global__ __launch_bounds__(128) void k0_fold(
    const float* __restrict__ W1, const float* __restrict__ W2,
    const float* __restrict__ Wa, const float* __restrict__ b1,
    float* __restrict__ WeT, float* __restrict__ beff)
{
  const int h = blockIdx.x / 65, oi = blockIdx.x % 65;
  const int d = threadIdx.x;
  const float* W1r = W1 + (size_t)h * 16384 + (size_t)d * 128;
  float acc = 0.f, p;
  if (oi < 64) {
    const float* w2c = W2 + (size_t)h * 8192 + oi;
#pragma unroll 8
    for (int kc = 0; kc < 32; kc++) {
      f32x4 wv = *(const f32x4*)(W1r + kc * 4);
      acc += wv[0] * w2c[(size_t)(kc * 4 + 0) * 64];
      acc += wv[1] * w2c[(size_t)(kc * 4 + 1) * 64];
      acc += wv[2] * w2c[(size_t)(kc * 4 + 2) * 64];
      acc += wv[3] * w2c[(size_t)(kc * 4 + 3) * 64];
    }
    p = b1[h * 128 + d] * w2c[(size_t)d * 64];
  } else {
    const float* wac = Wa + h * 128;
#pragma unroll 8
    for (int kc = 0; kc < 32; kc++) {
      f32x4 wv = *(const f32x4*)(W1r + kc * 4);
      f32x4 av = *(const f32x4*)(wac + kc * 4);
      acc += wv[0] * av[0] + wv[1] * av[1] + wv[2] * av[2] + wv[3] * av[3];
    }
    p = b1[h * 128 + d] * wac[d];
  }
  WeT[(size_t)h * 9216 + (size_t)d * 72 + oi] = acc;
  // block-reduce p (128 threads = 2 waves)
  for (int off = 32; off > 0; off >>= 1) p += __shfl_down(p, off, 64);
  __shared__ float r2s[2];
  if ((d & 63) == 0) r2s[d >> 6] = p;
  __syncthreads();
  if (d == 0) beff[h * 72 + oi] = r2s[0] + r2s[1];
}

// ---------------------------------------------------------------------------
// K1: per 8 nodes: P,q = nf @ WeT + beff  (weights pre-folded by k0)
// Output PqT bf16 [288][4096]: row h*72+o (o<64)=P, +64=q_hi, +65=q_lo
// 256 threads = 4 head-groups x 64 cols; each thread owns 8 nodes for (h,o).
// ---------------------------------------------------------------------------
__global__ __launch_bounds__(256) void k1_prep(
    const float* __restrict__ nf, const float* __restrict__ WeT,
    const float* __restrict__ beff, unsigned short* __restrict__ PqT)
{
  __shared__ float nf_s[8][132];
  const int n0 = blockIdx.x * 8;
  const int t = threadIdx.x;
  {
    int row = t >> 5, col = (t * 4) & 127;
    *(f32x4*)&nf_s[row][col] = *(const f32x4*)(nf + (size_t)(n0 + row) * 128 + col);
  }
  __syncthreads();
  const int h = t >> 6, o = t & 63;
  const float* wp = WeT + (size_t)h * 9216 + o;
  float acc[8];
  {
    float b = beff[h * 72 + o];
#pragma unroll
    for (int n = 0; n < 8; n++) acc[n] = b;
  }
  for (int dc = 0; dc < 32; dc++) {
    f32x4 nv[8];
#pragma unroll
    for (int n = 0; n < 8; n++) nv[n] = *(const f32x4*)&nf_s[n][dc * 4];
#pragma unroll
    for (int i = 0; i < 4; i++) {
      float wv = wp[(size_t)(dc * 4 + i) * 72];
#pragma unroll
      for (int n = 0; n < 8; n++) acc[n] += nv[n][i] * wv;
    }
  }
  {
    unsigned short b[8];
#pragma unroll
    for (int n = 0; n < 8; n++) b[n] = f2bf(acc[n]);
    u32x4 pk;
    pk[0] = (uint32_t)b[0] | ((uint32_t)b[1] << 16);
    pk[1] = (uint32_t)b[2] | ((uint32_t)b[3] << 16);
    pk[2] = (uint32_t)b[4] | ((uint32_t)b[5] << 16);
    pk[3] = (uint32_t)b[6] | ((uint32_t)b[7] << 16);
    *(u32x4*)(&PqT[(size_t)(h * 72 + o) * 4096 + n0]) = pk;
  }
  // q pass: rows 64 (hi) and 65 (lo), plus zero the pad rows 66..71
  if (t < 32) {
    const int qh = t >> 3, qn = t & 7;
    const float* wq = WeT + (size_t)qh * 9216 + 64;
    float a = beff[qh * 72 + 64];
    for (int d = 0; d < 128; d++) a += nf_s[qn][d] * wq[(size_t)d * 72];
    unsigned short hi = f2bf(a);
    unsigned short lo = f2bf(a - bf2f(hi));
    PqT[(size_t)(qh * 72 + 64) * 4096 + n0 + qn] = hi;
    PqT[(size_t)(qh * 72 + 65) * 4096 + n0 + qn] = lo;
  }
  if (t < 96) {  // 4 heads * 6 pad rows * 4 stores of 2 nodes
    const int ph = t / 24, pr = (t / 4) % 6, pn = (t & 3) * 2;
    *(uint32_t*)&PqT[(size_t)(ph * 72 + 66 + pr) * 4096 + n0 + pn] = 0u;
  }
}

// ---------------------------------------------------------------------------
// K2: C[16384][288] = inc^T (f32->bf16 hi+lo on the fly) @ PqT^T
// MFMA 16x16x32 bf16. BM=64 (edges), BK=64 (nodes), full N=288 per block;
// 256 threads = 4 waves (2x2), each wave computes 32e x 144c = 2x9 fragments.
// inc_lo correction only on ni={4,8} (the q score columns) -> fp32-grade scores.
// Epilogue: compact scores s[h][e] = C[e][qhi]+C[e][qlo] via shfl_xor pairing.
// ---------------------------------------------------------------------------
__global__ __launch_bounds__(256) void k2_gemm(
    const float* __restrict__ inc, const unsigned short* __restrict__ PqT,
    float* __restrict__ C, float* __restrict__ sbuf)
{
  __shared__ unsigned short As[64 * 64];    // 8 KB (inc hi)
  __shared__ unsigned short AsLo[64 * 64];  // 8 KB (inc lo residual)
  __shared__ unsigned short Bs[288 * 72];   // 41472 B
  const int t = threadIdx.x;
  const int lane = t & 63, w = t >> 6;
  const int wr = w & 1, wc = w >> 1;
  const int e0 = blockIdx.x * 64;
  const int eq = t & 15, kq = t >> 4;

  f32x4 acc[2][9];
  for (int mi = 0; mi < 2; mi++)
    for (int ni = 0; ni < 9; ni++)
      acc[mi][ni] = (f32x4){0.f, 0.f, 0.f, 0.f};

  f32x4 av[4];
  u32x4 bv[9];

  auto load_tiles = [&](int ks) {
    const float* ap = inc + (size_t)(ks * 64 + kq * 4) * 16384 + e0 + eq * 4;
#pragma unroll
    for (int r = 0; r < 4; r++)
      av[r] = *(const f32x4*)(ap + (size_t)r * 16384);
#pragma unroll
    for (int j = 0; j < 9; j++) {
      int f = t + 256 * j; int c = f >> 3, q8 = f & 7;
      bv[j] = *(const u32x4*)(PqT + (size_t)c * 4096 + ks * 64 + q8 * 8);
    }
  };
  auto store_tiles = [&]() {
#pragma unroll
    for (int i = 0; i < 4; i++) {
      int e = 4 * eq + i;
      int p = ((kq >> 1) + eq + 4 * i) & 7;  // chunk rotation: p = kc + perm(e)
      u16x4 wv, wl;
      wv[0] = f2bf(av[0][i]); wv[1] = f2bf(av[1][i]);
      wv[2] = f2bf(av[2][i]); wv[3] = f2bf(av[3][i]);
      wl[0] = f2bf(av[0][i] - bf2f(wv[0]));
      wl[1] = f2bf(av[1][i] - bf2f(wv[1]));
      wl[2] = f2bf(av[2][i] - bf2f(wv[2]));
      wl[3] = f2bf(av[3][i] - bf2f(wv[3]));
      *(u16x4*)(&As[e * 64 + p * 8 + (kq & 1) * 4]) = wv;
      *(u16x4*)(&AsLo[e * 64 + p * 8 + (kq & 1) * 4]) = wl;
    }
#pragma unroll
    for (int j = 0; j < 9; j++) {
      int f = t + 256 * j; int c = f >> 3, q8 = f & 7;
      *(u32x4*)(&Bs[c * 72 + q8 * 8]) = bv[j];
    }
  };
  auto compute = [&]() {
#pragma unroll
    for (int ksub = 0; ksub < 2; ksub++) {
      short8 afr[2], aflo[2];
      const int q = lane >> 4;
#pragma unroll
      for (int mi = 0; mi < 2; mi++) {
        int e = wr * 32 + mi * 16 + (lane & 15);
        int p = ((4 * ksub + q) + (e >> 2) + 4 * (e & 3)) & 7;
        afr[mi]  = *(const short8*)(&As[e * 64 + p * 8]);
        aflo[mi] = *(const short8*)(&AsLo[e * 64 + p * 8]);
      }
#pragma unroll
      for (int ni = 0; ni < 9; ni++) {
        int c = wc * 144 + ni * 16 + (lane & 15);
        const short8 bfr = *(const short8*)(&Bs[c * 72 + 32 * ksub + 8 * q]);
        acc[0][ni] = __builtin_amdgcn_mfma_f32_16x16x32_bf16(afr[0], bfr, acc[0][ni], 0, 0, 0);
        acc[1][ni] = __builtin_amdgcn_mfma_f32_16x16x32_bf16(afr[1], bfr, acc[1][ni], 0, 0, 0);
        if (ni == 4 || ni == 8) {  // fragments holding the q score columns
          acc[0][ni] = __builtin_amdgcn_mfma_f32_16x16x32_bf16(aflo[0], bfr, acc[0][ni], 0, 0, 0);
          acc[1][ni] = __builtin_amdgcn_mfma_f32_16x16x32_bf16(aflo[1], bfr, acc[1][ni], 0, 0, 0);
        }
      }
    }
  };

  load_tiles(0);
  for (int ks = 0; ks < 64; ks++) {
    __syncthreads();
    store_tiles();
    __syncthreads();
    if (ks < 63) load_tiles(ks + 1);
    compute();
  }

#pragma unroll
  for (int mi = 0; mi < 2; mi++)
#pragma unroll
    for (int ni = 0; ni < 9; ni++)
#pragma unroll
      for (int r = 0; r < 4; r++) {
        int e = e0 + wr * 32 + mi * 16 + (lane >> 4) * 4 + r;
        int c = wc * 144 + ni * 16 + (lane & 15);
        C[(size_t)e * CSTR + c] = acc[mi][ni][r];
      }

  // compact scores: s[head][e] = qhi + qlo columns
  const int l15 = lane & 15;
#pragma unroll
  for (int mi = 0; mi < 2; mi++)
#pragma unroll
    for (int r = 0; r < 4; r++) {
      int e = e0 + wr * 32 + mi * 16 + (lane >> 4) * 4 + r;
      {
        float v = acc[mi][4][r]; float vp = __shfl_xor(v, 1);
        if (l15 == 0) sbuf[(wc * 2 + 0) * 16384 + e] = v + vp;
      }
      {
        float v = acc[mi][8][r]; float vp = __shfl_xor(v, 1);
        if (l15 == 8) sbuf[(wc * 2 + 1) * 16384 + e] = v + vp;
      }
    }
}

// ---------------------------------------------------------------------------
// K3: per head: scores = leaky_relu(s + ba), softmax -> coeff.
// Also initializes the atomic min/max buffers for k4.
// ---------------------------------------------------------------------------
__global__ __launch_bounds__(1024) void k3_softmax(
    const float* __restrict__ sbuf, const float* __restrict__ ba,
    float* __restrict__ coeff, uint32_t* __restrict__ pmn_a,
    uint32_t* __restrict__ pmx_a)
{
  const int h = blockIdx.x, t = threadIdx.x;
  if (t < 64) { pmn_a[h * 64 + t] = 0xFFFFFFFFu; pmx_a[h * 64 + t] = 0u; }
  __shared__ float red[16];
  float vals[16];
  float mx = -1e30f;
  const float bav = ba[h];
#pragma unroll
  for (int i = 0; i < 16; i++) {
    float s = sbuf[h * 16384 + t + 1024 * i] + bav;
    s = (s > 0.f) ? s : 0.2f * s;
    vals[i] = s;
    mx = fmaxf(mx, s);
  }
  for (int off = 32; off > 0; off >>= 1) mx = fmaxf(mx, __shfl_xor(mx, off, 64));
  if ((t & 63) == 0) red[t >> 6] = mx;
  __syncthreads();
  float gmx = red[0];
  for (int i = 1; i < 16; i++) gmx = fmaxf(gmx, red[i]);
  float total = 0.f;
#pragma unroll
  for (int i = 0; i < 16; i++) { vals[i] = expf(vals[i] - gmx); total += vals[i]; }
  __syncthreads();
  for (int off = 32; off > 0; off >>= 1) total += __shfl_xor(total, off, 64);
  if ((t & 63) == 0) red[t >> 6] = total;
  __syncthreads();
  float gs = 0.f;
  for (int i = 0; i < 16; i++) gs += red[i];
  float inv = 1.f / gs;
#pragma unroll
  for (int i = 0; i < 16; i++) coeff[h * 16384 + t + 1024 * i] = vals[i] * inv;
}

// ---------------------------------------------------------------------------
// K4: per-column (h,o) min/max over all edges of u = coeff*C (b2 cancels),
// finished with order-preserving atomicMin/Max (no second reduce kernel).
// ---------------------------------------------------------------------------
__global__ __launch_bounds__(256) void k4_minmax(
    const float* __restrict__ C, const float* __restrict__ coeff,
    uint32_t* __restrict__ pmn_a, uint32_t* __restrict__ pmx_a)
{
  const int t = threadIdx.x, blk = blockIdx.x;
  const int h = t >> 6, o = t & 63, c = h * 72 + o;
  const int e0 = blk * 64;
  float mn = 1e30f, mx = -1e30f;
  for (int e = 0; e < 64; e++) {
    float u = coeff[h * 16384 + e0 + e] * C[(size_t)(e0 + e) * CSTR + c];
    mn = fminf(mn, u); mx = fmaxf(mx, u);
  }
  atomicMin(&pmn_a[t], fenc(mn));
  atomicMax(&pmx_a[t], fenc(mx));
}

// ---------------------------------------------------------------------------
// K5: 16 edges/block: cat = relu((coeff*C - mn)*inv); out = cat@Wout + bout
// ---------------------------------------------------------------------------
__global__ __launch_bounds__(256) void k5_out(
    const float* __restrict__ C, const float* __restrict__ coeff,
    const uint32_t* __restrict__ pmn_a, const uint32_t* __restrict__ pmx_a,
    const float* __restrict__ Wout, const float* __restrict__ bout,
    float* __restrict__ out)
{
  __shared__ float cat[16][256];
  const int t = threadIdx.x;
  const int e0 = blockIdx.x * 16;
  {
    const int h = t >> 6, o = t & 63, c = h * 72 + o;
    const float mn = fdec(pmn_a[t]);
    const float inv = 1.f / (fdec(pmx_a[t]) - mn + 1e-8f);
#pragma unroll
    for (int el = 0; el < 16; el++) {
      float u = coeff[h * 16384 + e0 + el] * C[(size_t)(e0 + el) * CSTR + c];
      float vn = (u - mn) * inv;
      cat[el][t] = vn > 0.f ? vn : 0.f;
    }
  }
  __syncthreads();
  {
    const int od = t & 63, eg = t >> 6;
    float b = bout[od];
    float a0 = b, a1 = b, a2 = b, a3 = b;
    for (int hc = 0; hc < 256; hc++) {
      float wv = Wout[(size_t)hc * 64 + od];
      a0 += cat[eg * 4 + 0][hc] * wv;
      a1 += cat[eg * 4 + 1][hc] * wv;
      a2 += cat[eg * 4 + 2][hc] * wv;
      a3 += cat[eg * 4 + 3][hc] * wv;
    }
    out[(size_t)(e0 + eg * 4 + 0) * 64 + od] = a0;
    out[(size_t)(e0 + eg * 4 + 1) * 64 + od] = a1;
    out[(size_t)(e0 + eg * 4 + 2) * 64 + od] = a2;
    out[(size_t)(e0 + eg * 4 + 3) * 64 + od] = a3;
  }
}

// ---------------------------------------------------------------------------
extern "C" void kernel_launch(void* const* d_in, const int* in_sizes, int n_in,
                              void* d_out, int out_size, void* d_ws, size_t ws_size,
                              hipStream_t stream) {
  const float* nf   = (const float*)d_in[0];
  const float* inc  = (const float*)d_in[1];
  const float* W1   = (const float*)d_in[2];
  const float* b1   = (const float*)d_in[3];
  const float* Wa   = (const float*)d_in[4];
  const float* ba   = (const float*)d_in[5];
  // d_in[6] = W2 used in k0; d_in[7] = b2 cancels exactly in min-max norm
  const float* W2   = (const float*)d_in[6];
  const float* Wout = (const float*)d_in[8];
  const float* bout = (const float*)d_in[9];
  float* out = (float*)d_out;

  char* ws = (char*)d_ws;
  unsigned short* PqT = (unsigned short*)(ws);            // 288*4096*2   = 2359296
  float* C      = (float*)(ws + 2359296);                 // 16384*288*4  = 18874368
  float* coeff  = (float*)(ws + 21233664);                // 4*16384*4    = 262144
  float* sbuf   = (float*)(ws + 21495808);                // 4*16384*4    = 262144
  float* WeT    = (float*)(ws + 21757952);                // 4*128*72*4   = 147456
  float* beff   = (float*)(ws + 21905408);                // 4*72*4       (pad 4096)
  uint32_t* pmn_a = (uint32_t*)(ws + 21909504);           // 256*4
  uint32_t* pmx_a = (uint32_t*)(ws + 21910528);           // 256*4

  k0_fold<<<260, 128, 0, stream>>>(W1, W2, Wa, b1, WeT, beff);
  k1_prep<<<512, 256, 0, stream>>>(nf, WeT, beff, PqT);
  k2_gemm<<<256, 256, 0, stream>>>(inc, PqT, C, sbuf);
  k3_softmax<<<4, 1024, 0, stream>>>(sbuf, ba, coeff, pmn_a, pmx_a);
  k4_minmax<<<256, 256, 0, stream>>>(C, coeff, pmn_a, pmx_a);
  k5_out<<<1024, 256, 0, stream>>>(C, coeff, pmn_a, pmx_a, Wout, bout, out);
}

// Round 4
// 452.726 us; speedup vs baseline: 1.2243x; 1.0258x over previous
//
#include <hip/hip_runtime.h>
#include <stdint.h>

// Problem constants
#define NODES 4096
#define EDGES 16384
#define CSTR  288   // k2 logical col count: 4 heads * 72 (64 P + qhi + qlo + 6 pad)

typedef __attribute__((ext_vector_type(4))) float    f32x4;
typedef __attribute__((ext_vector_type(8))) short    short8;
typedef __attribute__((ext_vector_type(4))) uint32_t u32x4;
typedef __attribute__((ext_vector_type(4))) unsigned short u16x4;

__device__ __forceinline__ unsigned short f2bf(float f) {
  union { float f; uint32_t u; } v; v.f = f;
  uint32_t u = v.u;
  return (unsigned short)((u + 0x7fffu + ((u >> 16) & 1u)) >> 16);  // RTNE
}
__device__ __forceinline__ float bf2f(unsigned short s) {
  union { uint32_t u; float f; } v; v.u = ((uint32_t)s) << 16;
  return v.f;
}
// order-preserving float <-> uint mapping for atomic min/max
__device__ __forceinline__ uint32_t fenc(float f) {
  uint32_t u = __float_as_uint(f);
  return (u >> 31) ? ~u : (u | 0x80000000u);
}
__device__ __forceinline__ float fdec(uint32_t k) {
  return (k & 0x80000000u) ? __uint_as_float(k ^ 0x80000000u) : __uint_as_float(~k);
}

// ---------------------------------------------------------------------------
// K0: fold weights through the linear chain + transpose Wout to bf16.
// Blocks 0..259: WeT[h][d][72] (o<64 -> (W1@W2)[d][o]; o==64 -> (W1@Wa)[d])
//                beff[h][72]   (b1@W2 / b1.Wa)
// Blocks 260..292: WoutT bf16 [64 od][264 k] (k>=256 zero-padded)
// ---------------------------------------------------------------------------
__global__ __launch_bounds__(128) void k0_fold(
    const float* __restrict__ W1, const float* __restrict__ W2,
    const float* __restrict__ Wa, const float* __restrict__ b1,
    const float* __restrict__ Wout,
    float* __restrict__ WeT, float* __restrict__ beff,
    unsigned short* __restrict__ WoutT)
{
  if (blockIdx.x >= 260) {
    int qi = (blockIdx.x - 260) * 128 + threadIdx.x;  // 0..4223
    if (qi < 4224) {
      int od = qi / 66, kq = qi % 66;
      u16x4 v;
#pragma unroll
      for (int j = 0; j < 4; j++) {
        int k = kq * 4 + j;
        v[j] = (k < 256) ? f2bf(Wout[(size_t)k * 64 + od]) : (unsigned short)0;
      }
      *(u16x4*)&WoutT[od * 264 + kq * 4] = v;
    }
    return;
  }
  const int h = blockIdx.x / 65, oi = blockIdx.x % 65;
  const int d = threadIdx.x;
  const float* W1r = W1 + (size_t)h * 16384 + (size_t)d * 128;
  float acc = 0.f, p;
  if (oi < 64) {
    const float* w2c = W2 + (size_t)h * 8192 + oi;
#pragma unroll 8
    for (int kc = 0; kc < 32; kc++) {
      f32x4 wv = *(const f32x4*)(W1r + kc * 4);
      acc += wv[0] * w2c[(size_t)(kc * 4 + 0) * 64];
      acc += wv[1] * w2c[(size_t)(kc * 4 + 1) * 64];
      acc += wv[2] * w2c[(size_t)(kc * 4 + 2) * 64];
      acc += wv[3] * w2c[(size_t)(kc * 4 + 3) * 64];
    }
    p = b1[h * 128 + d] * w2c[(size_t)d * 64];
  } else {
    const float* wac = Wa + h * 128;
#pragma unroll 8
    for (int kc = 0; kc < 32; kc++) {
      f32x4 wv = *(const f32x4*)(W1r + kc * 4);
      f32x4 av = *(const f32x4*)(wac + kc * 4);
      acc += wv[0] * av[0] + wv[1] * av[1] + wv[2] * av[2] + wv[3] * av[3];
    }
    p = b1[h * 128 + d] * wac[d];
  }
  WeT[(size_t)h * 9216 + (size_t)d * 72 + oi] = acc;
  for (int off = 32; off > 0; off >>= 1) p += __shfl_down(p, off, 64);
  __shared__ float r2s[2];
  if ((d & 63) == 0) r2s[d >> 6] = p;
  __syncthreads();
  if (d == 0) beff[h * 72 + oi] = r2s[0] + r2s[1];
}

// ---------------------------------------------------------------------------
// K1: per 8 nodes: P,q = nf @ WeT + beff  (weights pre-folded by k0)
// 128 threads = 4 heads x 32; each thread owns 2 columns (oo, oo+32) x 8 nodes
// -> halves the per-block LDS broadcast instruction count vs 1 col/thread.
// ---------------------------------------------------------------------------
__global__ __launch_bounds__(128) void k1_prep(
    const float* __restrict__ nf, const float* __restrict__ WeT,
    const float* __restrict__ beff, unsigned short* __restrict__ PqT)
{
  __shared__ float nf_s[8][132];
  const int n0 = blockIdx.x * 8;
  const int t = threadIdx.x;
#pragma unroll
  for (int i = 0; i < 2; i++) {
    int idx = t + 128 * i;   // 256 f32x4 quads
    int row = idx >> 5, c4 = idx & 31;
    *(f32x4*)&nf_s[row][c4 * 4] = *(const f32x4*)(nf + (size_t)(n0 + row) * 128 + c4 * 4);
  }
  __syncthreads();
  const int h = t >> 5, oo = t & 31;
  const float* wp = WeT + (size_t)h * 9216 + oo;
  float acc0[8], acc1[8];
  {
    float b0 = beff[h * 72 + oo], b1v = beff[h * 72 + oo + 32];
#pragma unroll
    for (int n = 0; n < 8; n++) { acc0[n] = b0; acc1[n] = b1v; }
  }
  for (int dc = 0; dc < 32; dc++) {
    f32x4 nv[8];
#pragma unroll
    for (int n = 0; n < 8; n++) nv[n] = *(const f32x4*)&nf_s[n][dc * 4];
#pragma unroll
    for (int i = 0; i < 4; i++) {
      float w0 = wp[(size_t)(dc * 4 + i) * 72];
      float w1 = wp[(size_t)(dc * 4 + i) * 72 + 32];
#pragma unroll
      for (int n = 0; n < 8; n++) {
        acc0[n] += nv[n][i] * w0;
        acc1[n] += nv[n][i] * w1;
      }
    }
  }
  {
    unsigned short b[8];
#pragma unroll
    for (int n = 0; n < 8; n++) b[n] = f2bf(acc0[n]);
    u32x4 pk;
    pk[0] = (uint32_t)b[0] | ((uint32_t)b[1] << 16);
    pk[1] = (uint32_t)b[2] | ((uint32_t)b[3] << 16);
    pk[2] = (uint32_t)b[4] | ((uint32_t)b[5] << 16);
    pk[3] = (uint32_t)b[6] | ((uint32_t)b[7] << 16);
    *(u32x4*)(&PqT[(size_t)(h * 72 + oo) * 4096 + n0]) = pk;
#pragma unroll
    for (int n = 0; n < 8; n++) b[n] = f2bf(acc1[n]);
    pk[0] = (uint32_t)b[0] | ((uint32_t)b[1] << 16);
    pk[1] = (uint32_t)b[2] | ((uint32_t)b[3] << 16);
    pk[2] = (uint32_t)b[4] | ((uint32_t)b[5] << 16);
    pk[3] = (uint32_t)b[6] | ((uint32_t)b[7] << 16);
    *(u32x4*)(&PqT[(size_t)(h * 72 + oo + 32) * 4096 + n0]) = pk;
  }
  // q rows 64 (hi) / 65 (lo)
  if (t < 32) {
    const int qh = t >> 3, qn = t & 7;
    const float* wq = WeT + (size_t)qh * 9216 + 64;
    float a = beff[qh * 72 + 64];
    for (int d = 0; d < 128; d++) a += nf_s[qn][d] * wq[(size_t)d * 72];
    unsigned short hi = f2bf(a);
    unsigned short lo = f2bf(a - bf2f(hi));
    PqT[(size_t)(qh * 72 + 64) * 4096 + n0 + qn] = hi;
    PqT[(size_t)(qh * 72 + 65) * 4096 + n0 + qn] = lo;
  }
  if (t < 96) {  // zero pad rows 66..71
    const int ph = t / 24, pr = (t / 4) % 6, pn = (t & 3) * 2;
    *(uint32_t*)&PqT[(size_t)(ph * 72 + 66 + pr) * 4096 + n0 + pn] = 0u;
  }
}

// ---------------------------------------------------------------------------
// K2: C = inc^T (f32->bf16 hi+lo on the fly) @ PqT^T, MFMA 16x16x32 bf16.
// BM=64, BK=64, full N=288/block; 256 thr = 4 waves (2x2), wave = 32e x 144c.
// inc_lo correction only on ni={4,8} (q score cols) -> fp32-grade scores.
// Epilogue: P cols -> compact bf16 Cb[16384][256]; scores -> fp32 sbuf.
// ---------------------------------------------------------------------------
__global__ __launch_bounds__(256) void k2_gemm(
    const float* __restrict__ inc, const unsigned short* __restrict__ PqT,
    unsigned short* __restrict__ Cb, float* __restrict__ sbuf)
{
  __shared__ unsigned short As[64 * 64];    // 8 KB (inc hi)
  __shared__ unsigned short AsLo[64 * 64];  // 8 KB (inc lo residual)
  __shared__ unsigned short Bs[288 * 72];   // 41472 B
  const int t = threadIdx.x;
  const int lane = t & 63, w = t >> 6;
  const int wr = w & 1, wc = w >> 1;
  const int e0 = blockIdx.x * 64;
  const int eq = t & 15, kq = t >> 4;

  f32x4 acc[2][9];
  for (int mi = 0; mi < 2; mi++)
    for (int ni = 0; ni < 9; ni++)
      acc[mi][ni] = (f32x4){0.f, 0.f, 0.f, 0.f};

  f32x4 av[4];
  u32x4 bv[9];

  auto load_tiles = [&](int ks) {
    const float* ap = inc + (size_t)(ks * 64 + kq * 4) * 16384 + e0 + eq * 4;
#pragma unroll
    for (int r = 0; r < 4; r++)
      av[r] = *(const f32x4*)(ap + (size_t)r * 16384);
#pragma unroll
    for (int j = 0; j < 9; j++) {
      int f = t + 256 * j; int c = f >> 3, q8 = f & 7;
      bv[j] = *(const u32x4*)(PqT + (size_t)c * 4096 + ks * 64 + q8 * 8);
    }
  };
  auto store_tiles = [&]() {
#pragma unroll
    for (int i = 0; i < 4; i++) {
      int e = 4 * eq + i;
      int p = ((kq >> 1) + eq + 4 * i) & 7;  // chunk rotation swizzle
      u16x4 wv, wl;
      wv[0] = f2bf(av[0][i]); wv[1] = f2bf(av[1][i]);
      wv[2] = f2bf(av[2][i]); wv[3] = f2bf(av[3][i]);
      wl[0] = f2bf(av[0][i] - bf2f(wv[0]));
      wl[1] = f2bf(av[1][i] - bf2f(wv[1]));
      wl[2] = f2bf(av[2][i] - bf2f(wv[2]));
      wl[3] = f2bf(av[3][i] - bf2f(wv[3]));
      *(u16x4*)(&As[e * 64 + p * 8 + (kq & 1) * 4]) = wv;
      *(u16x4*)(&AsLo[e * 64 + p * 8 + (kq & 1) * 4]) = wl;
    }
#pragma unroll
    for (int j = 0; j < 9; j++) {
      int f = t + 256 * j; int c = f >> 3, q8 = f & 7;
      *(u32x4*)(&Bs[c * 72 + q8 * 8]) = bv[j];
    }
  };
  auto compute = [&]() {
#pragma unroll
    for (int ksub = 0; ksub < 2; ksub++) {
      short8 afr[2], aflo[2];
      const int q = lane >> 4;
#pragma unroll
      for (int mi = 0; mi < 2; mi++) {
        int e = wr * 32 + mi * 16 + (lane & 15);
        int p = ((4 * ksub + q) + (e >> 2) + 4 * (e & 3)) & 7;
        afr[mi]  = *(const short8*)(&As[e * 64 + p * 8]);
        aflo[mi] = *(const short8*)(&AsLo[e * 64 + p * 8]);
      }
#pragma unroll
      for (int ni = 0; ni < 9; ni++) {
        int c = wc * 144 + ni * 16 + (lane & 15);
        const short8 bfr = *(const short8*)(&Bs[c * 72 + 32 * ksub + 8 * q]);
        acc[0][ni] = __builtin_amdgcn_mfma_f32_16x16x32_bf16(afr[0], bfr, acc[0][ni], 0, 0, 0);
        acc[1][ni] = __builtin_amdgcn_mfma_f32_16x16x32_bf16(afr[1], bfr, acc[1][ni], 0, 0, 0);
        if (ni == 4 || ni == 8) {
          acc[0][ni] = __builtin_amdgcn_mfma_f32_16x16x32_bf16(aflo[0], bfr, acc[0][ni], 0, 0, 0);
          acc[1][ni] = __builtin_amdgcn_mfma_f32_16x16x32_bf16(aflo[1], bfr, acc[1][ni], 0, 0, 0);
        }
      }
    }
  };

  load_tiles(0);
  for (int ks = 0; ks < 64; ks++) {
    __syncthreads();
    store_tiles();
    __syncthreads();
    if (ks < 63) load_tiles(ks + 1);
    compute();
  }

  // Epilogue: P columns -> compact bf16 Cb[e][h*64+o]
#pragma unroll
  for (int mi = 0; mi < 2; mi++)
#pragma unroll
    for (int ni = 0; ni < 9; ni++) {
      int cl = wc * 144 + ni * 16 + (lane & 15);
      int hl = cl / 72, o = cl - hl * 72;
      if (o < 64) {
        int cbcol = hl * 64 + o;
#pragma unroll
        for (int r = 0; r < 4; r++) {
          int e = e0 + wr * 32 + mi * 16 + (lane >> 4) * 4 + r;
          Cb[(size_t)e * 256 + cbcol] = f2bf(acc[mi][ni][r]);
        }
      }
    }

  // compact scores: s[head][e] = qhi + qlo columns
  const int l15 = lane & 15;
#pragma unroll
  for (int mi = 0; mi < 2; mi++)
#pragma unroll
    for (int r = 0; r < 4; r++) {
      int e = e0 + wr * 32 + mi * 16 + (lane >> 4) * 4 + r;
      {
        float v = acc[mi][4][r]; float vp = __shfl_xor(v, 1);
        if (l15 == 0) sbuf[(wc * 2 + 0) * 16384 + e] = v + vp;
      }
      {
        float v = acc[mi][8][r]; float vp = __shfl_xor(v, 1);
        if (l15 == 8) sbuf[(wc * 2 + 1) * 16384 + e] = v + vp;
      }
    }
}

// ---------------------------------------------------------------------------
// K3: per head: scores = leaky_relu(s + ba), softmax -> coeff.
// Also initializes the atomic min/max buffers for k4.
// ---------------------------------------------------------------------------
__global__ __launch_bounds__(1024) void k3_softmax(
    const float* __restrict__ sbuf, const float* __restrict__ ba,
    float* __restrict__ coeff, uint32_t* __restrict__ pmn_a,
    uint32_t* __restrict__ pmx_a)
{
  const int h = blockIdx.x, t = threadIdx.x;
  if (t < 64) { pmn_a[h * 64 + t] = 0xFFFFFFFFu; pmx_a[h * 64 + t] = 0u; }
  __shared__ float red[16];
  float vals[16];
  float mx = -1e30f;
  const float bav = ba[h];
#pragma unroll
  for (int i = 0; i < 16; i++) {
    float s = sbuf[h * 16384 + t + 1024 * i] + bav;
    s = (s > 0.f) ? s : 0.2f * s;
    vals[i] = s;
    mx = fmaxf(mx, s);
  }
  for (int off = 32; off > 0; off >>= 1) mx = fmaxf(mx, __shfl_xor(mx, off, 64));
  if ((t & 63) == 0) red[t >> 6] = mx;
  __syncthreads();
  float gmx = red[0];
  for (int i = 1; i < 16; i++) gmx = fmaxf(gmx, red[i]);
  float total = 0.f;
#pragma unroll
  for (int i = 0; i < 16; i++) { vals[i] = expf(vals[i] - gmx); total += vals[i]; }
  __syncthreads();
  for (int off = 32; off > 0; off >>= 1) total += __shfl_xor(total, off, 64);
  if ((t & 63) == 0) red[t >> 6] = total;
  __syncthreads();
  float gs = 0.f;
  for (int i = 0; i < 16; i++) gs += red[i];
  float inv = 1.f / gs;
#pragma unroll
  for (int i = 0; i < 16; i++) coeff[h * 16384 + t + 1024 * i] = vals[i] * inv;
}

// ---------------------------------------------------------------------------
// K4: per-column (h,o) min/max over edges of u = coeff*Cb (b2 cancels),
// order-preserving atomicMin/Max finish. Column = t directly (compact Cb).
// ---------------------------------------------------------------------------
__global__ __launch_bounds__(256) void k4_minmax(
    const unsigned short* __restrict__ Cb, const float* __restrict__ coeff,
    uint32_t* __restrict__ pmn_a, uint32_t* __restrict__ pmx_a)
{
  const int t = threadIdx.x, blk = blockIdx.x;
  const int h = t >> 6;
  const int e0 = blk * 64;
  float mn = 1e30f, mx = -1e30f;
  for (int e = 0; e < 64; e++) {
    float u = coeff[h * 16384 + e0 + e] * bf2f(Cb[(size_t)(e0 + e) * 256 + t]);
    mn = fminf(mn, u); mx = fmaxf(mx, u);
  }
  atomicMin(&pmn_a[t], fenc(mn));
  atomicMax(&pmx_a[t], fenc(mx));
}

// ---------------------------------------------------------------------------
// K5: 64 edges/block. Phase 1: cat bf16 [64][264] in LDS =
// relu((coeff*Cb - mn)*inv). Phase 2: MFMA out = cat @ WoutT^T + bout.
// B-fragments gathered directly from global WoutT (33 KB, L1/L2-hot).
// ---------------------------------------------------------------------------
__global__ __launch_bounds__(256) void k5_out(
    const unsigned short* __restrict__ Cb, const float* __restrict__ coeff,
    const uint32_t* __restrict__ pmn_a, const uint32_t* __restrict__ pmx_a,
    const unsigned short* __restrict__ WoutT, const float* __restrict__ bout,
    float* __restrict__ out)
{
  __shared__ unsigned short cat_s[64 * 264];  // 33792 B, odd-16 stride
  const int t = threadIdx.x;
  const int e0 = blockIdx.x * 64;
  const int cq = t & 63, w64 = t >> 6;
  // per-thread fixed 4 columns: decode mn/inv once
  float mn[4], inv[4];
#pragma unroll
  for (int j = 0; j < 4; j++) {
    uint32_t a = pmn_a[cq * 4 + j], b = pmx_a[cq * 4 + j];
    mn[j] = fdec(a);
    inv[j] = 1.f / (fdec(b) - mn[j] + 1e-8f);
  }
  const int hh = cq >> 4;
#pragma unroll
  for (int i = 0; i < 16; i++) {
    int e = w64 + 4 * i;
    float cf = coeff[hh * 16384 + e0 + e];
    u16x4 cb = *(const u16x4*)(Cb + (size_t)(e0 + e) * 256 + cq * 4);
    unsigned short o4[4];
#pragma unroll
    for (int j = 0; j < 4; j++) {
      float u = cf * bf2f(cb[j]);
      float vn = (u - mn[j]) * inv[j];
      vn = vn > 0.f ? vn : 0.f;
      o4[j] = f2bf(vn);
    }
    u16x4 pk; pk[0] = o4[0]; pk[1] = o4[1]; pk[2] = o4[2]; pk[3] = o4[3];
    *(u16x4*)&cat_s[e * 264 + cq * 4] = pk;
  }
  __syncthreads();
  const int lane = t & 63, w = t >> 6, l15 = lane & 15, q = lane >> 4;
  f32x4 oacc[4];
#pragma unroll
  for (int ni = 0; ni < 4; ni++) oacc[ni] = (f32x4){0.f, 0.f, 0.f, 0.f};
#pragma unroll
  for (int kstep = 0; kstep < 8; kstep++) {
    short8 afr = *(const short8*)&cat_s[(w * 16 + l15) * 264 + kstep * 32 + q * 8];
#pragma unroll
    for (int ni = 0; ni < 4; ni++) {
      short8 bfr = *(const short8*)(WoutT + (size_t)(ni * 16 + l15) * 264 + kstep * 32 + q * 8);
      oacc[ni] = __builtin_amdgcn_mfma_f32_16x16x32_bf16(afr, bfr, oacc[ni], 0, 0, 0);
    }
  }
#pragma unroll
  for (int ni = 0; ni < 4; ni++) {
    float bo = bout[ni * 16 + l15];
#pragma unroll
    for (int r = 0; r < 4; r++) {
      int e = e0 + w * 16 + q * 4 + r;
      out[(size_t)e * 64 + ni * 16 + l15] = oacc[ni][r] + bo;
    }
  }
}

// ---------------------------------------------------------------------------
extern "C" void kernel_launch(void* const* d_in, const int* in_sizes, int n_in,
                              void* d_out, int out_size, void* d_ws, size_t ws_size,
                              hipStream_t stream) {
  const float* nf   = (const float*)d_in[0];
  const float* inc  = (const float*)d_in[1];
  const float* W1   = (const float*)d_in[2];
  const float* b1   = (const float*)d_in[3];
  const float* Wa   = (const float*)d_in[4];
  const float* ba   = (const float*)d_in[5];
  const float* W2   = (const float*)d_in[6];
  // d_in[7] = b2: cancels exactly in min-max normalization
  const float* Wout = (const float*)d_in[8];
  const float* bout = (const float*)d_in[9];
  float* out = (float*)d_out;

  char* ws = (char*)d_ws;
  unsigned short* PqT   = (unsigned short*)(ws);            // 288*4096*2   = 2359296
  unsigned short* Cb    = (unsigned short*)(ws + 2359296);  // 16384*256*2  = 8388608
  float* coeff          = (float*)(ws + 10747904);          // 4*16384*4    = 262144
  float* sbuf           = (float*)(ws + 11010048);          // 4*16384*4    = 262144
  float* WeT            = (float*)(ws + 11272192);          // 4*128*72*4   = 147456
  float* beff           = (float*)(ws + 11419648);          // 4*72*4 (pad 4096)
  unsigned short* WoutT = (unsigned short*)(ws + 11423744); // 64*264*2 = 33792 (pad 36864)
  uint32_t* pmn_a       = (uint32_t*)(ws + 11460608);       // 256*4 (pad 4096)
  uint32_t* pmx_a       = (uint32_t*)(ws + 11464704);       // 256*4

  k0_fold<<<293, 128, 0, stream>>>(W1, W2, Wa, b1, Wout, WeT, beff, WoutT);
  k1_prep<<<512, 128, 0, stream>>>(nf, WeT, beff, PqT);
  k2_gemm<<<256, 256, 0, stream>>>(inc, PqT, Cb, sbuf);
  k3_softmax<<<4, 1024, 0, stream>>>(sbuf, ba, coeff, pmn_a, pmx_a);
  k4_minmax<<<256, 256, 0, stream>>>(Cb, coeff, pmn_a, pmx_a);
  k5_out<<<256, 256, 0, stream>>>(Cb, coeff, pmn_a, pmx_a, WoutT, bout, out);
}